// Round 1
// baseline (616.732 us; speedup 1.0000x reference)
//
#include <hip/hip_runtime.h>
#include <stdint.h>

#define NSTEPS 40
#define SBS 264   // LDS state-row stride in elements (256 + 8 pad; 528 B, 16B-aligned)

typedef float    floatx4  __attribute__((ext_vector_type(4)));
typedef __bf16   bf16x8   __attribute__((ext_vector_type(8)));
typedef __bf16   bf16x4   __attribute__((ext_vector_type(4)));
typedef uint32_t uint32x2 __attribute__((ext_vector_type(2)));

__device__ __forceinline__ __bf16 f2bf(float f){
  union { float f; uint32_t u; } v; v.f = f;
  uint32_t r = v.u + 0x7FFFu + ((v.u >> 16) & 1u);   // RNE (prep kernels only)
  union { uint16_t s; __bf16 b; } o; o.s = (uint16_t)(r >> 16);
  return o.b;
}
__device__ __forceinline__ float bf2f(__bf16 b){
  union { uint16_t s; __bf16 b; } i; i.b = b;
  union { uint32_t u; float f; } o; o.u = ((uint32_t)i.s) << 16;
  return o.f;
}
__device__ __forceinline__ uint32_t cvt_pk_bf16(float lo, float hi){
  uint32_t d;
  asm("v_cvt_pk_bf16_f32 %0, %1, %2" : "=v"(d) : "v"(lo), "v"(hi));
  return d;
}
__device__ __forceinline__ float fast_tanh(float x){
  float e = __expf(2.0f * x);
  return __builtin_fmaf(-2.0f, __builtin_amdgcn_rcpf(e + 1.0f), 1.0f);
}

// ---- prep1: bf16-cast + transpose weights; beta = b2 @ W1 (fp32) ----
__global__ void prep_kernel(const float* __restrict__ Ws,
                            const float* __restrict__ W1,
                            const float* __restrict__ W2,
                            const float* __restrict__ b2,
                            __bf16* __restrict__ WsT,
                            __bf16* __restrict__ W1T,
                            __bf16* __restrict__ W2T,
                            float* __restrict__ beta){
  int tid = blockIdx.x * blockDim.x + threadIdx.x;
  int stride = gridDim.x * blockDim.x;
  for (int i = tid; i < 512*256; i += stride){
    int k = i >> 8, n = i & 255;
    WsT[n*512 + k] = f2bf(Ws[i]);
  }
  for (int i = tid; i < 256*256; i += stride){
    int k = i >> 8, n = i & 255;
    W1T[n*256 + k] = f2bf(W1[i]);
    W2T[n*256 + k] = f2bf(W2[i]);
  }
  if (blockIdx.x == 0){
    int j = threadIdx.x;            // 256 threads
    float acc = 0.f;
    for (int l = 0; l < 256; ++l)
      acc = __builtin_fmaf(b2[l], W1[l*256 + j], acc);
    beta[j] = acc;
  }
}

// ---- prep2: MT[j][i] = (W2@W1)[i][j] (fp32 dot, bf16 store) ----
__global__ void prep_mt(const float* __restrict__ W1,
                        const float* __restrict__ W2,
                        __bf16* __restrict__ MT){
  __shared__ float w2row[256];
  const int i = blockIdx.x;
  const int j = threadIdx.x;
  w2row[j] = W2[i*256 + j];
  __syncthreads();
  float acc = 0.f;
  for (int l = 0; l < 256; ++l)
    acc = __builtin_fmaf(w2row[l], W1[l*256 + j], acc);
  MT[j*256 + i] = f2bf(acc);
}

// Fused ODE kernel, round 12: TWO BARRIER DOMAINS PER CU.
// Re-tile: 1024 blocks x 16 batch, 256 thr = 4 waves; wave = 64 latent x 16 batch.
// - Mf resident 128 regs/thread (64 rows x 256 k bf16 / 64 lanes); accums shrink
//   (nt=1) so total ~225 regs -> still 2 waves/SIMD, but LDS drops 103->26 KB
//   so TWO blocks co-reside per CU: independent barriers overlap each other's
//   drain (the 160 per-slot syncs were ~40% idle at 1 block/CU).
// - LDS B-read amplification 8x -> 4x (wave owns 64 latent rows): per-slot z
//   re-read traffic halves.
// - b1 folded into carried Y; beta resident in regs; vector (pk) bookkeeping.
__global__ __launch_bounds__(256, 2)
void ode_kernel(const float* __restrict__ x,
                const float* __restrict__ b_state,
                const float* __restrict__ W1full,   // 257x256 fp32 (row 256 = t row)
                const float* __restrict__ b1,
                const float* __restrict__ b2,
                const float* __restrict__ Wout,     // 256x18 fp32
                const float* __restrict__ bout,
                const __bf16* __restrict__ WsT,     // [256][512]
                const __bf16* __restrict__ W1Tg,    // [256][256]
                const __bf16* __restrict__ W2Tg,    // [256][256]
                const __bf16* __restrict__ MTg,     // [256][256]
                const float* __restrict__ betag,    // [256]
                float* __restrict__ out)
{
  __shared__ __align__(16) __bf16 lds_sb0[16*SBS];   // 8.25 KB  z double-buffer A
  __shared__ __align__(16) __bf16 lds_sb1[16*SBS];   // 8.25 KB  z double-buffer B
  __shared__ __align__(16) __bf16 lds_h0[16*SBS];    // 8.25 KB  h0 (kept to epilogue)
  __shared__ __align__(16) float  lds_wt[256];       // 1 KB     time row of W_dyn1

  const int tid  = threadIdx.x;
  const int wave = tid >> 6;       // 0..3
  const int lane = tid & 63;
  const int c16  = lane & 15;      // batch col within tile
  const int q    = lane >> 4;      // 0..3
  const int L0   = wave * 64;      // this wave's latent-row base (64 rows)
  const int m0   = blockIdx.x * 16;

  lds_wt[tid] = W1full[256*256 + tid];   // 256 threads exactly

  // ---- addressing ----
  int arow[4];
  #pragma unroll
  for (int mt = 0; mt < 4; ++mt) arow[mt] = L0 + mt*16 + c16;  // A-frag rows
  const int brow  = c16 * SBS;     // B batch-row base in z tiles
  const int rbase = L0 + 4*q;      // C/D latent-row base (mt adds 16)

  const float dt  = 1.0f / NSTEPS;
  const float hdt = 0.5f * dt;
  const float dt6 = dt / 6.0f;
  const floatx4 vzero = {0.f, 0.f, 0.f, 0.f};

  // ---- phase 0: h0 = tanh(x@Ws + bs) -> lds_h0 ----
  {
    floatx4 p0[4];
    #pragma unroll
    for (int mt = 0; mt < 4; ++mt)
      p0[mt] = *(const floatx4*)&b_state[rbase + mt*16];
    #pragma unroll 1
    for (int kt = 0; kt < 16; ++kt){
      const float* px = &x[(size_t)(m0 + c16)*512 + kt*32 + q*8];
      floatx4 f0 = *(const floatx4*)px;
      floatx4 f1 = *(const floatx4*)(px + 4);
      union { uint32_t u[4]; bf16x8 v; } pk;
      pk.u[0] = cvt_pk_bf16(f0[0], f0[1]);
      pk.u[1] = cvt_pk_bf16(f0[2], f0[3]);
      pk.u[2] = cvt_pk_bf16(f1[0], f1[1]);
      pk.u[3] = cvt_pk_bf16(f1[2], f1[3]);
      bf16x8 b = pk.v;
      #pragma unroll
      for (int mt = 0; mt < 4; ++mt){
        bf16x8 a = *(const bf16x8*)&WsT[arow[mt]*512 + kt*32 + q*8];
        p0[mt] = __builtin_amdgcn_mfma_f32_16x16x32_bf16(a, b, p0[mt], 0, 0, 0);
      }
    }
    #pragma unroll
    for (int mt = 0; mt < 4; ++mt){
      float v0 = fast_tanh(p0[mt][0]);
      float v1 = fast_tanh(p0[mt][1]);
      float v2 = fast_tanh(p0[mt][2]);
      float v3 = fast_tanh(p0[mt][3]);
      uint32x2 wv = { cvt_pk_bf16(v0, v1), cvt_pk_bf16(v2, v3) };
      *(uint32x2*)&lds_h0[brow + rbase + mt*16] = wv;
    }
  }
  __syncthreads();

  // ---- Y = h0 @ W1 + b1 (b1 folded into the carried state) ----
  floatx4 Y[4];
  #pragma unroll
  for (int mt = 0; mt < 4; ++mt)
    Y[mt] = *(const floatx4*)&b1[rbase + mt*16];
  #pragma unroll
  for (int kt = 0; kt < 8; ++kt){
    bf16x8 b = *(const bf16x8*)&lds_h0[brow + kt*32 + q*8];
    #pragma unroll
    for (int mt = 0; mt < 4; ++mt){
      bf16x8 a = *(const bf16x8*)&W1Tg[arow[mt]*256 + kt*32 + q*8];
      Y[mt] = __builtin_amdgcn_mfma_f32_16x16x32_bf16(a, b, Y[mt], 0, 0, 0);
    }
  }

  // ---- resident M^T fragments (128 regs) + resident beta (16 regs) ----
  bf16x8 Mf[4][8];
  #pragma unroll
  for (int mt = 0; mt < 4; ++mt)
    #pragma unroll
    for (int kt = 0; kt < 8; ++kt)
      Mf[mt][kt] = *(const bf16x8*)&MTg[arow[mt]*256 + kt*32 + q*8];
  floatx4 betav[4];
  #pragma unroll
  for (int mt = 0; mt < 4; ++mt)
    betav[mt] = *(const floatx4*)&betag[rbase + mt*16];
  #pragma unroll
  for (int mt = 0; mt < 4; ++mt){
    #pragma unroll
    for (int kt = 0; kt < 8; ++kt)
      asm volatile("" : "+v"(Mf[mt][kt]));
    asm volatile("" : "+v"(betav[mt]));
  }

  // ---- slot 0: z0 = tanh(Y) (t=0, cin=0), w = z0 -> SB0 ----
  floatx4 w[4], sM[4];
  #pragma unroll
  for (int mt = 0; mt < 4; ++mt){
    floatx4 zv;
    #pragma unroll
    for (int r = 0; r < 4; ++r) zv[r] = fast_tanh(Y[mt][r]);
    w[mt]  = zv;
    sM[mt] = vzero;
    uint32x2 wv = { cvt_pk_bf16(zv[0], zv[1]), cvt_pk_bf16(zv[2], zv[3]) };
    *(uint32x2*)&lds_sb0[brow + rbase + mt*16] = wv;
  }
  __syncthreads();

  // ---- main loop: slots i = 1..159, ONE GEMM + ONE barrier each ----
  #pragma unroll 1
  for (int i = 1; i < NSTEPS*4; ++i){
    const int e = i & 3;
    const float cin = (e == 0) ? 0.0f : ((e == 3) ? dt : hdt);
    const float te  = dt * (float)(i >> 2) + cin;
    const float wz  = (e == 1 || e == 2) ? 2.0f : 1.0f;
    const __bf16* sbR = ((i & 1) == 1) ? lds_sb0 : lds_sb1;  // holds z_{i-1}
    __bf16*       sbW = ((i & 1) == 1) ? lds_sb1 : lds_sb0;  // gets  z_i

    // GEMM: p = beta + z_{i-1} @ M   (A = M^T resident, beta resident)
    floatx4 p[4];
    #pragma unroll
    for (int mt = 0; mt < 4; ++mt) p[mt] = betav[mt];
    #pragma unroll
    for (int kt = 0; kt < 8; ++kt){
      bf16x8 b = *(const bf16x8*)&sbR[brow + kt*32 + q*8];
      #pragma unroll
      for (int mt = 0; mt < 4; ++mt)
        p[mt] = __builtin_amdgcn_mfma_f32_16x16x32_bf16(Mf[mt][kt], b, p[mt], 0, 0, 0);
    }

    // RK4 bookkeeping (p = q_{i-1} + beta); vector form -> v_pk_fma_f32
    if (e == 0){
      #pragma unroll
      for (int mt = 0; mt < 4; ++mt)
        Y[mt] += dt6 * (sM[mt] + p[mt]);
    } else if (e == 1){
      #pragma unroll
      for (int mt = 0; mt < 4; ++mt) sM[mt] = p[mt];
    } else {
      #pragma unroll
      for (int mt = 0; mt < 4; ++mt) sM[mt] += 2.0f * p[mt];
    }

    // z_i = tanh(Y + cin*p + te*wt); w += wz*z; write -> sbW
    #pragma unroll
    for (int mt = 0; mt < 4; ++mt){
      floatx4 wtv  = *(const floatx4*)&lds_wt[rbase + mt*16];
      floatx4 argv = Y[mt] + p[mt]*cin + wtv*te;
      floatx4 zv;
      #pragma unroll
      for (int r = 0; r < 4; ++r) zv[r] = fast_tanh(argv[r]);
      w[mt] = zv*wz + w[mt];
      uint32x2 wv = { cvt_pk_bf16(zv[0], zv[1]), cvt_pk_bf16(zv[2], zv[3]) };
      *(uint32x2*)&sbW[brow + rbase + mt*16] = wv;
    }
    __syncthreads();
  }

  // ---- epilogue: h_T = h0 + (dt6*w) @ W2 + b2, then out = h_T @ Wout ----
  // pack dt6*w -> SB0 (z_158 dead; its readers finished before slot-159 barrier)
  #pragma unroll
  for (int mt = 0; mt < 4; ++mt){
    floatx4 wv4 = w[mt] * dt6;
    uint32x2 wv = { cvt_pk_bf16(wv4[0], wv4[1]), cvt_pk_bf16(wv4[2], wv4[3]) };
    *(uint32x2*)&lds_sb0[brow + rbase + mt*16] = wv;
  }
  __syncthreads();
  {
    floatx4 hF[4];
    #pragma unroll
    for (int mt = 0; mt < 4; ++mt)
      hF[mt] = *(const floatx4*)&b2[rbase + mt*16];
    #pragma unroll
    for (int kt = 0; kt < 8; ++kt){
      bf16x8 b = *(const bf16x8*)&lds_sb0[brow + kt*32 + q*8];
      #pragma unroll
      for (int mt = 0; mt < 4; ++mt){
        bf16x8 a = *(const bf16x8*)&W2Tg[arow[mt]*256 + kt*32 + q*8];
        hF[mt] = __builtin_amdgcn_mfma_f32_16x16x32_bf16(a, b, hF[mt], 0, 0, 0);
      }
    }
    // + h0, write h_T -> SB1 (z_159 never read; safe to overwrite)
    #pragma unroll
    for (int mt = 0; mt < 4; ++mt){
      bf16x4 h0v = *(const bf16x4*)&lds_h0[brow + rbase + mt*16];
      #pragma unroll
      for (int r = 0; r < 4; ++r) hF[mt][r] += bf2f(h0v[r]);
      uint32x2 wv = { cvt_pk_bf16(hF[mt][0], hF[mt][1]),
                      cvt_pk_bf16(hF[mt][2], hF[mt][3]) };
      *(uint32x2*)&lds_sb1[brow + rbase + mt*16] = wv;
    }
  }
  __syncthreads();
  {
    const int r  = tid & 15;         // batch row within block
    const int og = tid >> 4;         // 0..15: output col; og<2 also does og+16
    float acc0 = 0.f;
    for (int c = 0; c < 32; ++c){
      bf16x8 h8 = *(const bf16x8*)&lds_sb1[r*SBS + c*8];
      #pragma unroll
      for (int j = 0; j < 8; ++j)
        acc0 += bf2f(h8[j]) * Wout[(c*8 + j)*18 + og];
    }
    out[(size_t)(m0 + r)*18 + og] = acc0 + bout[og];
    if (og < 2){
      const int o2 = 16 + og;
      float acc1 = 0.f;
      for (int c = 0; c < 32; ++c){
        bf16x8 h8 = *(const bf16x8*)&lds_sb1[r*SBS + c*8];
        #pragma unroll
        for (int j = 0; j < 8; ++j)
          acc1 += bf2f(h8[j]) * Wout[(c*8 + j)*18 + o2];
      }
      out[(size_t)(m0 + r)*18 + o2] = acc1 + bout[o2];
    }
  }
}

extern "C" void kernel_launch(void* const* d_in, const int* in_sizes, int n_in,
                              void* d_out, int out_size, void* d_ws, size_t ws_size,
                              hipStream_t stream){
  const float* x   = (const float*)d_in[0];
  const float* Ws  = (const float*)d_in[1];
  const float* bs  = (const float*)d_in[2];
  const float* W1  = (const float*)d_in[3];
  const float* b1  = (const float*)d_in[4];
  const float* W2  = (const float*)d_in[5];
  const float* b2  = (const float*)d_in[6];
  const float* Wo  = (const float*)d_in[7];
  const float* bo  = (const float*)d_in[8];
  float* out = (float*)d_out;

  __bf16* WsT  = (__bf16*)d_ws;          // 256x512 bf16 = 256 KB
  __bf16* W1T  = WsT + 512*256;          // 256x256 bf16 = 128 KB
  __bf16* W2T  = W1T + 256*256;          // 256x256 bf16 = 128 KB
  __bf16* MT   = W2T + 256*256;          // 256x256 bf16 = 128 KB
  float*  beta = (float*)(MT + 256*256); // 256 fp32 = 1 KB

  prep_kernel<<<128, 256, 0, stream>>>(Ws, W1, W2, b2, WsT, W1T, W2T, beta);
  prep_mt<<<256, 256, 0, stream>>>(W1, W2, MT);
  ode_kernel<<<1024, 256, 0, stream>>>(x, bs, W1, b1, b2, Wo, bo,
                                       WsT, W1T, W2T, MT, beta, out);
}